// Round 1
// baseline (321.712 us; speedup 1.0000x reference)
//
#include <hip/hip_runtime.h>
#include <hip/hip_bf16.h>

// Problem constants (match reference)
#define BATCH 128
#define TLEN  65536
#define EDIM  512
#define SMAX  512

// ---------------------------------------------------------------------------
// Kernel 1: per-sample mask popcount -> n_valid; also writes padding_mask out.
// mask arrives as int32 (harness convention: integer -> const int*), 0/1.
// ---------------------------------------------------------------------------
__global__ __launch_bounds__(256) void mask_len_kernel(
    const int* __restrict__ mask, const int* __restrict__ branch_idx,
    int* __restrict__ n_valid, float* __restrict__ out_mask) {
  const int b = blockIdx.x;
  const int t = threadIdx.x;
  const int4* row = (const int4*)(mask + (size_t)b * TLEN);
  int s = 0;
  // 65536 ints = 16384 int4; 64 per thread
  for (int i = t; i < TLEN / 4; i += 256) {
    int4 v = row[i];
    s += (v.x != 0) + (v.y != 0) + (v.z != 0) + (v.w != 0);
  }
  // wave (64-lane) reduction
  #pragma unroll
  for (int off = 32; off > 0; off >>= 1) s += __shfl_down(s, off);
  __shared__ int partial[4];
  __shared__ int nv_sh;
  if ((t & 63) == 0) partial[t >> 6] = s;
  __syncthreads();
  if (t == 0) {
    int len = partial[0] + partial[1] + partial[2] + partial[3];
    int w = 128 << branch_idx[b];         // 128/256/512
    int nv = len / w;                     // == min(len//w, S_b, SMAX) since len<=T
    n_valid[b] = nv;
    nv_sh = nv;
  }
  __syncthreads();
  const int nv = nv_sh;
  out_mask[(size_t)b * SMAX + t]       = (t < nv)       ? 1.0f : 0.0f;
  out_mask[(size_t)b * SMAX + 256 + t] = (256 + t < nv) ? 1.0f : 0.0f;
}

// ---------------------------------------------------------------------------
// Kernel 2: per-sample GEMM  C(64x64 tile) = A(sxw) * W^T + bias, masked.
// A[s][k] = signal[b][s*w+k] (contiguous!), B[k][e] = W[e][k] (row-major in k).
// LDS stored transposed (As[k][m]) with stride 68 (16B-aligned, conflict-free
// b128 compute reads: A-side 4 distinct addrs x16 broadcast, W-side 2-way max).
// ---------------------------------------------------------------------------
__global__ __launch_bounds__(256) void gemm_kernel(
    const float* __restrict__ signal, const int* __restrict__ branch_idx,
    const int* __restrict__ n_valid_arr,
    const float* __restrict__ W0, const float* __restrict__ bias0,
    const float* __restrict__ W1, const float* __restrict__ bias1,
    const float* __restrict__ W2, const float* __restrict__ bias2,
    float* __restrict__ out) {
  const int et = blockIdx.x;   // 0..7  (e tile of 64)
  const int st = blockIdx.y;   // 0..7  (s tile of 64)
  const int b  = blockIdx.z;   // 0..127
  const int t  = threadIdx.x;
  const int nv = n_valid_arr[b];
  const int s0 = st * 64;
  float* outp = out + ((size_t)b * SMAX + s0) * EDIM + et * 64;

  if (s0 >= nv) {
    // entire tile masked -> zero-fill (needed: harness poisons d_out)
    const float4 z = make_float4(0.f, 0.f, 0.f, 0.f);
    #pragma unroll
    for (int i = 0; i < 4; ++i) {
      int idx = t + i * 256;            // 0..1023 -> 64 rows x 16 float4
      int r = idx >> 4, c = idx & 15;
      *(float4*)(outp + (size_t)r * EDIM + c * 4) = z;
    }
    return;
  }

  const int bi = branch_idx[b];
  const float* Wp = (bi == 0) ? W0 : (bi == 1) ? W1 : W2;
  const float* bp = (bi == 0) ? bias0 : (bi == 1) ? bias1 : bias2;
  const int w = 128 << bi;

  __shared__ float As[32][68];   // transposed: As[k][m], stride 68 floats
  __shared__ float Bs[32][68];   // Bs[k][e_local]

  float acc[4][4];
  #pragma unroll
  for (int i = 0; i < 4; ++i)
    #pragma unroll
    for (int j = 0; j < 4; ++j) acc[i][j] = 0.f;

  const int ty = t >> 4;   // 0..15 -> 4 rows each
  const int tx = t & 15;   // 0..15 -> 4 cols each
  const float* sigb = signal + (size_t)b * TLEN;

  for (int k0 = 0; k0 < w; k0 += 32) {
    // stage A tile (64 m x 32 k) and W tile (64 e x 32 k) -> LDS transposed
    #pragma unroll
    for (int l = 0; l < 2; ++l) {
      int idx = t + l * 256;            // 0..511
      int m   = idx >> 3;               // 0..63
      int kk  = (idx & 7) * 4;          // 0,4,...,28
      int s   = s0 + m;
      float4 av = make_float4(0.f, 0.f, 0.f, 0.f);
      if (s < nv)  // also guarantees s < S_b -> in-bounds read
        av = *(const float4*)(sigb + (size_t)s * w + k0 + kk);
      int e = et * 64 + m;
      float4 wv = *(const float4*)(Wp + (size_t)e * w + k0 + kk);
      As[kk + 0][m] = av.x; As[kk + 1][m] = av.y;
      As[kk + 2][m] = av.z; As[kk + 3][m] = av.w;
      Bs[kk + 0][m] = wv.x; Bs[kk + 1][m] = wv.y;
      Bs[kk + 2][m] = wv.z; Bs[kk + 3][m] = wv.w;
    }
    __syncthreads();
    #pragma unroll
    for (int kk = 0; kk < 32; ++kk) {
      float4 a4 = *(const float4*)&As[kk][ty * 4];
      float4 b4 = *(const float4*)&Bs[kk][tx * 4];
      float a[4] = {a4.x, a4.y, a4.z, a4.w};
      float bb[4] = {b4.x, b4.y, b4.z, b4.w};
      #pragma unroll
      for (int i = 0; i < 4; ++i)
        #pragma unroll
        for (int j = 0; j < 4; ++j)
          acc[i][j] += a[i] * bb[j];
    }
    __syncthreads();
  }

  // epilogue: add bias, mask rows >= nv (exact zeros, no bias there)
  float4 bias4 = *(const float4*)(bp + et * 64 + tx * 4);
  #pragma unroll
  for (int i = 0; i < 4; ++i) {
    int s = s0 + ty * 4 + i;
    float4 r;
    if (s < nv) {
      r.x = acc[i][0] + bias4.x;
      r.y = acc[i][1] + bias4.y;
      r.z = acc[i][2] + bias4.z;
      r.w = acc[i][3] + bias4.w;
    } else {
      r = make_float4(0.f, 0.f, 0.f, 0.f);
    }
    *(float4*)(outp + (size_t)(ty * 4 + i) * EDIM + tx * 4) = r;
  }
}

extern "C" void kernel_launch(void* const* d_in, const int* in_sizes, int n_in,
                              void* d_out, int out_size, void* d_ws, size_t ws_size,
                              hipStream_t stream) {
  const float* signal = (const float*)d_in[0];
  const int*   mask   = (const int*)d_in[1];   // bool -> int32 per harness
  const int*   bidx   = (const int*)d_in[2];
  const float* W0 = (const float*)d_in[3];
  const float* b0 = (const float*)d_in[4];
  const float* W1 = (const float*)d_in[5];
  const float* b1 = (const float*)d_in[6];
  const float* W2 = (const float*)d_in[7];
  const float* b2 = (const float*)d_in[8];

  float* out_tokens = (float*)d_out;
  float* out_mask   = (float*)d_out + (size_t)BATCH * SMAX * EDIM;
  int*   n_valid    = (int*)d_ws;   // 128 ints

  mask_len_kernel<<<dim3(BATCH), dim3(256), 0, stream>>>(mask, bidx, n_valid, out_mask);
  gemm_kernel<<<dim3(8, 8, BATCH), dim3(256), 0, stream>>>(
      signal, bidx, n_valid, W0, b0, W1, b1, W2, b2, out_tokens);
}

// Round 2
// 259.157 us; speedup vs baseline: 1.2414x; 1.2414x over previous
//
#include <hip/hip_runtime.h>
#include <hip/hip_bf16.h>

#define BATCH 128
#define TLEN  65536
#define EDIM  512
#define SMAX  512

typedef __attribute__((ext_vector_type(8))) short   bf16x8;
typedef __attribute__((ext_vector_type(4))) float   floatx4;
typedef __attribute__((ext_vector_type(8))) ushort  ushort8;

#define LDS_STRIDE 40  // bf16 elems per row: 80 B, 16B-aligned, bank-spread

__device__ __forceinline__ ushort f2bf(float f) {
  __hip_bfloat16 h = __float2bfloat16(f);  // RNE
  return *reinterpret_cast<ushort*>(&h);
}

// ---------------------------------------------------------------------------
// Stage A: partial popcount of mask. grid (BATCH, 8), 256 thr.
// part[b*8+c] = sum of mask[b][c*8192 : (c+1)*8192]
// ---------------------------------------------------------------------------
__global__ __launch_bounds__(256) void mask_partial_kernel(
    const int* __restrict__ mask, int* __restrict__ part) {
  const int b = blockIdx.x, c = blockIdx.y, t = threadIdx.x;
  const int4* row = (const int4*)(mask + (size_t)b * TLEN + (size_t)c * 8192);
  int s = 0;
  #pragma unroll
  for (int i = 0; i < 8; ++i) {
    int4 v = row[t + i * 256];
    s += (v.x != 0) + (v.y != 0) + (v.z != 0) + (v.w != 0);
  }
  #pragma unroll
  for (int off = 32; off > 0; off >>= 1) s += __shfl_down(s, off);
  __shared__ int partial[4];
  if ((t & 63) == 0) partial[t >> 6] = s;
  __syncthreads();
  if (t == 0)
    part[b * 8 + c] = partial[0] + partial[1] + partial[2] + partial[3];
}

// ---------------------------------------------------------------------------
// Stage B: n_valid[b] = (sum part) / w; write padding_mask output. grid BATCH.
// ---------------------------------------------------------------------------
__global__ __launch_bounds__(256) void mask_final_kernel(
    const int* __restrict__ part, const int* __restrict__ branch_idx,
    int* __restrict__ n_valid, float* __restrict__ out_mask) {
  const int b = blockIdx.x, t = threadIdx.x;
  __shared__ int nv_sh;
  if (t == 0) {
    int len = 0;
    #pragma unroll
    for (int i = 0; i < 8; ++i) len += part[b * 8 + i];
    int w = 128 << branch_idx[b];
    int nv = len / w;
    n_valid[b] = nv;
    nv_sh = nv;
  }
  __syncthreads();
  const int nv = nv_sh;
  out_mask[(size_t)b * SMAX + t]       = (t < nv)       ? 1.0f : 0.0f;
  out_mask[(size_t)b * SMAX + 256 + t] = (256 + t < nv) ? 1.0f : 0.0f;
}

// ---------------------------------------------------------------------------
// MFMA GEMM: per sample b, C(SMAX x 512) = patches(S x w) @ W^T + bias,
// rows >= n_valid zeroed. 128x128 tile / block, 4 waves (2x2 of 64x64),
// 16x16x32 bf16 MFMA, BK=32, inline f32->bf16 conversion during staging.
// grid (4 e-tiles, 4 s-tiles, BATCH), 256 thr.
// ---------------------------------------------------------------------------
__global__ __launch_bounds__(256) void gemm_kernel(
    const float* __restrict__ signal, const int* __restrict__ branch_idx,
    const int* __restrict__ n_valid_arr,
    const float* __restrict__ W0, const float* __restrict__ bias0,
    const float* __restrict__ W1, const float* __restrict__ bias1,
    const float* __restrict__ W2, const float* __restrict__ bias2,
    float* __restrict__ out) {
  const int et = blockIdx.x;          // e tile (0..3), 128 wide
  const int st = blockIdx.y;          // s tile (0..3), 128 tall
  const int b  = blockIdx.z;
  const int t  = threadIdx.x;
  const int nv = n_valid_arr[b];
  const int s0 = st * 128;
  const int e0 = et * 128;
  float* outb = out + (size_t)b * SMAX * EDIM;

  if (s0 >= nv) {
    // fully-masked tile: zero-fill (harness poisons d_out every call)
    const float4 z = make_float4(0.f, 0.f, 0.f, 0.f);
    #pragma unroll
    for (int i = 0; i < 16; ++i) {
      int idx = t + i * 256;          // 0..4095 -> 128 rows x 32 float4
      int r = idx >> 5, c = idx & 31;
      *(float4*)(outb + (size_t)(s0 + r) * EDIM + e0 + c * 4) = z;
    }
    return;
  }
  // computing tile => s0 < nv <= S_b, and since both are multiples of 128,
  // rows s0..s0+127 < S_b -> all signal reads in-bounds.

  const int bi = branch_idx[b];
  const float* Wp = (bi == 0) ? W0 : (bi == 1) ? W1 : W2;
  const float* bp = (bi == 0) ? bias0 : (bi == 1) ? bias1 : bias2;
  const int w = 128 << bi;

  __shared__ __align__(16) ushort Abuf[128 * LDS_STRIDE];
  __shared__ __align__(16) ushort Bbuf[128 * LDS_STRIDE];

  const int wave   = t >> 6;
  const int lane   = t & 63;
  const int lane16 = lane & 15;
  const int quad   = lane >> 4;
  const int ws_ = (wave >> 1) * 64;   // wave's s offset in tile
  const int we_ = (wave & 1) * 64;    // wave's e offset in tile

  // staging assignment: row r (0..127), k-half h (0..1) -> 16 consecutive k
  const int r = t >> 1, h = t & 1;
  const float* asrc = signal + (size_t)b * TLEN + (size_t)(s0 + r) * w + h * 16;
  const float* bsrc = Wp + (size_t)(e0 + r) * w + h * 16;
  ushort* adst = &Abuf[r * LDS_STRIDE + h * 16];
  ushort* bdst = &Bbuf[r * LDS_STRIDE + h * 16];

  floatx4 acc[4][4];
  #pragma unroll
  for (int i = 0; i < 4; ++i)
    #pragma unroll
    for (int j = 0; j < 4; ++j) acc[i][j] = (floatx4)(0.f);

  for (int k0 = 0; k0 < w; k0 += 32) {
    // ---- stage A and B tiles (f32 -> bf16) ----
    {
      const float4* a4 = (const float4*)(asrc + k0);
      const float4* b4 = (const float4*)(bsrc + k0);
      float4 av0 = a4[0], av1 = a4[1], av2 = a4[2], av3 = a4[3];
      float4 bv0 = b4[0], bv1 = b4[1], bv2 = b4[2], bv3 = b4[3];
      ushort8 p0, p1, q0, q1;
      p0[0]=f2bf(av0.x); p0[1]=f2bf(av0.y); p0[2]=f2bf(av0.z); p0[3]=f2bf(av0.w);
      p0[4]=f2bf(av1.x); p0[5]=f2bf(av1.y); p0[6]=f2bf(av1.z); p0[7]=f2bf(av1.w);
      p1[0]=f2bf(av2.x); p1[1]=f2bf(av2.y); p1[2]=f2bf(av2.z); p1[3]=f2bf(av2.w);
      p1[4]=f2bf(av3.x); p1[5]=f2bf(av3.y); p1[6]=f2bf(av3.z); p1[7]=f2bf(av3.w);
      q0[0]=f2bf(bv0.x); q0[1]=f2bf(bv0.y); q0[2]=f2bf(bv0.z); q0[3]=f2bf(bv0.w);
      q0[4]=f2bf(bv1.x); q0[5]=f2bf(bv1.y); q0[6]=f2bf(bv1.z); q0[7]=f2bf(bv1.w);
      q1[0]=f2bf(bv2.x); q1[1]=f2bf(bv2.y); q1[2]=f2bf(bv2.z); q1[3]=f2bf(bv2.w);
      q1[4]=f2bf(bv3.x); q1[5]=f2bf(bv3.y); q1[6]=f2bf(bv3.z); q1[7]=f2bf(bv3.w);
      *(ushort8*)adst = p0; *(ushort8*)(adst + 8) = p1;
      *(ushort8*)bdst = q0; *(ushort8*)(bdst + 8) = q1;
    }
    __syncthreads();
    // ---- MFMA on the tile ----
    bf16x8 af[4], bfr[4];
    #pragma unroll
    for (int i = 0; i < 4; ++i)
      af[i] = *(const bf16x8*)&Abuf[(ws_ + i * 16 + lane16) * LDS_STRIDE + quad * 8];
    #pragma unroll
    for (int j = 0; j < 4; ++j)
      bfr[j] = *(const bf16x8*)&Bbuf[(we_ + j * 16 + lane16) * LDS_STRIDE + quad * 8];
    #pragma unroll
    for (int i = 0; i < 4; ++i)
      #pragma unroll
      for (int j = 0; j < 4; ++j)
        acc[i][j] = __builtin_amdgcn_mfma_f32_16x16x32_bf16(af[i], bfr[j], acc[i][j], 0, 0, 0);
    __syncthreads();
  }

  // ---- epilogue: bias + row masking, f32 stores ----
  float bval[4];
  #pragma unroll
  for (int j = 0; j < 4; ++j) bval[j] = bp[e0 + we_ + j * 16 + lane16];
  #pragma unroll
  for (int i = 0; i < 4; ++i) {
    #pragma unroll
    for (int rr = 0; rr < 4; ++rr) {
      const int s_row = s0 + ws_ + i * 16 + quad * 4 + rr;
      const bool valid = s_row < nv;
      float* op = outb + (size_t)s_row * EDIM + e0 + we_ + lane16;
      #pragma unroll
      for (int j = 0; j < 4; ++j)
        op[j * 16] = valid ? (acc[i][j][rr] + bval[j]) : 0.f;
    }
  }
}

extern "C" void kernel_launch(void* const* d_in, const int* in_sizes, int n_in,
                              void* d_out, int out_size, void* d_ws, size_t ws_size,
                              hipStream_t stream) {
  const float* signal = (const float*)d_in[0];
  const int*   mask   = (const int*)d_in[1];
  const int*   bidx   = (const int*)d_in[2];
  const float* W0 = (const float*)d_in[3];
  const float* b0 = (const float*)d_in[4];
  const float* W1 = (const float*)d_in[5];
  const float* b1 = (const float*)d_in[6];
  const float* W2 = (const float*)d_in[7];
  const float* b2 = (const float*)d_in[8];

  float* out_tokens = (float*)d_out;
  float* out_mask   = (float*)d_out + (size_t)BATCH * SMAX * EDIM;
  int*   n_valid    = (int*)d_ws;             // 128 ints
  int*   part       = (int*)d_ws + 128;       // 128*8 ints

  mask_partial_kernel<<<dim3(BATCH, 8), dim3(256), 0, stream>>>(mask, part);
  mask_final_kernel<<<dim3(BATCH), dim3(256), 0, stream>>>(part, bidx, n_valid, out_mask);
  gemm_kernel<<<dim3(4, 4, BATCH), dim3(256), 0, stream>>>(
      signal, bidx, n_valid, W0, b0, W1, b1, W2, b2, out_tokens);
}